// Round 3
// baseline (2243.228 us; speedup 1.0000x reference)
//
#include <hip/hip_runtime.h>
#include <math.h>

#define EPS_NORM_F 1e-8f
#define EPS_SIGN_F 1e-6f

struct alignas(16) F4v { float a0, a1, a2, a3; };

// v += dpp_permute(v) with bound_ctrl=1 (invalid source lanes contribute 0).
// Reduction ladder (all within one wave):
//   0xB1 quad_perm[1,0,3,2]  : xor1
//   0x4E quad_perm[2,3,0,1]  : xor2
//   0x141 row_half_mirror    : fold quads within 8-group
//   0x140 row_mirror         : fold 8-groups -> every lane has its 16-row sum
//   0x142 row_bcast15        : row0 -> row1, row2 -> row3 (rows 0,2 add 0)
//   0x143 row_bcast31        : (row0+row1) -> rows 2,3 => lanes 48..63 = wave sum
template <int CTRL>
__device__ __forceinline__ float dpp_add(float v) {
  int p = __builtin_amdgcn_update_dpp(0, __float_as_int(v), CTRL, 0xF, 0xF, true);
  return v + __int_as_float(p);
}

__device__ __forceinline__ float wave_sum(float ps) {
  ps = dpp_add<0xB1>(ps);
  ps = dpp_add<0x4E>(ps);
  ps = dpp_add<0x141>(ps);
  ps = dpp_add<0x140>(ps);
  ps = dpp_add<0x142>(ps);
  ps = dpp_add<0x143>(ps);
  return ps;  // valid in lanes 48..63
}

// Raw barrier: waits LDS ops only (lgkmcnt), NOT vmcnt -> global prefetch of
// x[t+2] stays in flight across the per-step barrier. "memory" clobbers fence
// the compiler; s_barrier syncs the 4 waves.
__device__ __forceinline__ void sync_lds() {
  asm volatile("s_waitcnt lgkmcnt(0)" ::: "memory");
  __builtin_amdgcn_s_barrier();
  asm volatile("" ::: "memory");
}

__global__ __launch_bounds__(256) void me_scan(
    const float* __restrict__ x,
    const float* __restrict__ tape_init,
    const float* __restrict__ eta_p,
    const float* __restrict__ tb_p,
    float* __restrict__ out,
    int T, int D) {
  const int tid  = threadIdx.x;
  const int lane = tid & 63;
  const int wid  = tid >> 6;
  const int d0   = tid << 2;           // 4 consecutive dims per thread
  const int b    = blockIdx.x;

  __shared__ __align__(16) float red[2][4];  // double-buffered per-wave sums

  const float eta_abs = fabsf(eta_p[0]);
  const F4v tb = *(const F4v*)(tb_p + d0);

  const float* xb = x   + (size_t)b * (size_t)T * (size_t)D;
  float*       ob = out + (size_t)b * (size_t)T * (size_t)D;

  float s0, s1, s2, s3;

  // ---- s0 = renorm(tape_init) (identical for every batch) ----
  {
    F4v ti = *(const F4v*)(tape_init + d0);
    s0 = ti.a0; s1 = ti.a1; s2 = ti.a2; s3 = ti.a3;
    float ps = wave_sum((s0 * s0 + s1 * s1) + (s2 * s2 + s3 * s3));
    if (lane == 63) red[0][wid] = ps;
    sync_lds();
    F4v r = *(const F4v*)(&red[0][0]);
    float S = (r.a0 + r.a1) + (r.a2 + r.a3);
    float n = fmaxf(sqrtf(S), EPS_NORM_F);
    float inv = 1.0f / n;
    s0 *= inv; s1 *= inv; s2 *= inv; s3 *= inv;
  }

  // 2-deep prefetch of x rows (hides ~900cy HBM latency across 2 iterations)
  F4v ha = *(const F4v*)(xb + d0);
  F4v hb = *(const F4v*)(xb + (size_t)D + d0);

  #pragma unroll 2
  for (int t = 0; t < T; ++t) {
    const int tn = (t + 2 < T) ? (t + 2) : (T - 1);
    F4v hc = *(const F4v*)(xb + (size_t)tn * (size_t)D + d0);

    // ---- elementwise: c = h*s; u = s + eta*(c*[|c|>eps] + tb*[c<-eps]) ----
    float u0, u1, u2, u3;
    {
      float c;
      c = ha.a0 * s0;
      u0 = s0 + eta_abs * (((fabsf(c) > EPS_SIGN_F) ? c : 0.0f) + ((c < -EPS_SIGN_F) ? tb.a0 : 0.0f));
      c = ha.a1 * s1;
      u1 = s1 + eta_abs * (((fabsf(c) > EPS_SIGN_F) ? c : 0.0f) + ((c < -EPS_SIGN_F) ? tb.a1 : 0.0f));
      c = ha.a2 * s2;
      u2 = s2 + eta_abs * (((fabsf(c) > EPS_SIGN_F) ? c : 0.0f) + ((c < -EPS_SIGN_F) ? tb.a2 : 0.0f));
      c = ha.a3 * s3;
      u3 = s3 + eta_abs * (((fabsf(c) > EPS_SIGN_F) ? c : 0.0f) + ((c < -EPS_SIGN_F) ? tb.a3 : 0.0f));
    }

    // ---- ||u||^2: 6-level DPP wave sum -> 4-float LDS cross-wave combine ----
    float ps = wave_sum((u0 * u0 + u1 * u1) + (u2 * u2 + u3 * u3));
    const int slot = (t + 1) & 1;
    if (lane == 63) red[slot][wid] = ps;
    sync_lds();
    F4v r = *(const F4v*)(&red[slot][0]);
    float S = (r.a0 + r.a1) + (r.a2 + r.a3);

    float n = fmaxf(sqrtf(S), EPS_NORM_F);
    float inv = 1.0f / n;                 // precise IEEE div (no fast-math)

    s0 = u0 * inv; s1 = u1 * inv; s2 = u2 * inv; s3 = u3 * inv;

    F4v sv; sv.a0 = s0; sv.a1 = s1; sv.a2 = s2; sv.a3 = s3;
    *(F4v*)(ob + (size_t)t * (size_t)D + d0) = sv;

    ha = hb; hb = hc;
  }
}

extern "C" void kernel_launch(void* const* d_in, const int* in_sizes, int n_in,
                              void* d_out, int out_size, void* d_ws, size_t ws_size,
                              hipStream_t stream) {
  const float* x         = (const float*)d_in[0];
  const float* tape_init = (const float*)d_in[1];
  const float* eta       = (const float*)d_in[2];
  const float* tbias     = (const float*)d_in[3];
  float* out = (float*)d_out;

  const int D = in_sizes[1];            // 1024
  const int B = 8;                      // per setup_inputs
  const int T = in_sizes[0] / (B * D);  // 4096

  dim3 grid(B), block(D / 4);           // 256 threads = 4 waves
  hipLaunchKernelGGL(me_scan, grid, block, 0, stream,
                     x, tape_init, eta, tbias, out, T, D);
}

// Round 4
// 1799.316 us; speedup vs baseline: 1.2467x; 1.2467x over previous
//
#include <hip/hip_runtime.h>
#include <math.h>

#define EPS_NORM_F 1e-8f
#define EPS_SIGN_F 1e-6f

struct alignas(16) F4 { float v0, v1, v2, v3; };

// v += dpp_permute(v), bound_ctrl=1 (invalid lanes contribute 0).
// Ladder: xor1, xor2, row_half_mirror, row_mirror -> every lane has its
// 16-row sum; row_bcast15 + row_bcast31 -> lane 63 has the full wave sum.
// (HW-verified correct in round 3.)
template <int CTRL>
__device__ __forceinline__ float dpp_add(float v) {
  int p = __builtin_amdgcn_update_dpp(0, __float_as_int(v), CTRL, 0xF, 0xF, true);
  return v + __int_as_float(p);
}

__device__ __forceinline__ float wave_sum_bcast(float ps) {
  ps = dpp_add<0xB1>(ps);
  ps = dpp_add<0x4E>(ps);
  ps = dpp_add<0x141>(ps);
  ps = dpp_add<0x140>(ps);
  ps = dpp_add<0x142>(ps);
  ps = dpp_add<0x143>(ps);
  // full sum lives in lane 63; broadcast via SGPR
  return __int_as_float(__builtin_amdgcn_readlane(__float_as_int(ps), 63));
}

// One wave per batch chain. Each lane owns 16 dims: d = k*256 + lane*4 + j.
// State v is the PRE-renorm vector; normalization is deferred:
//   c > eps      <=>  h*v > eps*n        (thr = eps*n)
//   s + update   ==   inv*(v + eta*cc*m) + (tor ? eta*tb : 0)
// so the 1/n divide overlaps with the next step's compare/select work.
__global__ __launch_bounds__(64) void me_scan(
    const float* __restrict__ x,
    const float* __restrict__ tape_init,
    const float* __restrict__ eta_p,
    const float* __restrict__ tb_p,
    float* __restrict__ out,
    int T) {
  const int lane = threadIdx.x;   // 0..63
  const int b    = blockIdx.x;
  const int D    = 1024;

  const float eta_abs = fabsf(eta_p[0]);

  // eta * torque_bias, per-lane fragment
  float etb[4][4];
  {
    const F4* tbp = (const F4*)tb_p;
#pragma unroll
    for (int k = 0; k < 4; ++k) {
      F4 t4 = tbp[k * 64 + lane];
      etb[k][0] = eta_abs * t4.v0; etb[k][1] = eta_abs * t4.v1;
      etb[k][2] = eta_abs * t4.v2; etb[k][3] = eta_abs * t4.v3;
    }
  }

  const float* xb = x   + (size_t)b * (size_t)T * D;
  float*       ob = out + (size_t)b * (size_t)T * D;

  float v[4][4];
  float thr, inv;

  // ---- init: v = renorm(tape_init); then inv=1, thr=eps ----
  {
    const F4* tip = (const F4*)tape_init;
    float acc[4];
#pragma unroll
    for (int k = 0; k < 4; ++k) {
      F4 t4 = tip[k * 64 + lane];
      v[k][0] = t4.v0; v[k][1] = t4.v1; v[k][2] = t4.v2; v[k][3] = t4.v3;
      acc[k] = (t4.v0 * t4.v0 + t4.v1 * t4.v1) + (t4.v2 * t4.v2 + t4.v3 * t4.v3);
    }
    float S = wave_sum_bcast((acc[0] + acc[1]) + (acc[2] + acc[3]));
    float n = fmaxf(sqrtf(S), EPS_NORM_F);
    float r = 1.0f / n;
#pragma unroll
    for (int k = 0; k < 4; ++k)
#pragma unroll
      for (int j = 0; j < 4; ++j) v[k][j] *= r;
    inv = 1.0f;
    thr = EPS_SIGN_F;
  }

  // ---- 4-deep prefetch ring of x rows ----
  F4 h[4][4];   // h[slot][k]
#pragma unroll
  for (int i = 0; i < 4; ++i) {
    const F4* xr = (const F4*)(xb + (size_t)((i < T) ? i : (T - 1)) * D);
#pragma unroll
    for (int k = 0; k < 4; ++k) h[i][k] = xr[k * 64 + lane];
  }

  for (int tt = 0; tt < T; tt += 4) {
#pragma unroll
    for (int i = 0; i < 4; ++i) {
      const int t = tt + i;

      // 1) cc = h * v (consume slot i, then immediately refill it)
      float cc[4][4];
#pragma unroll
      for (int k = 0; k < 4; ++k) {
        cc[k][0] = h[i][k].v0 * v[k][0];
        cc[k][1] = h[i][k].v1 * v[k][1];
        cc[k][2] = h[i][k].v2 * v[k][2];
        cc[k][3] = h[i][k].v3 * v[k][3];
      }
      // 2) prefetch row t+4 into slot i (4 iterations of lead time)
      {
        const int tn = (t + 4 < T) ? (t + 4) : (T - 1);
        const F4* xr = (const F4*)(xb + (size_t)tn * D);
#pragma unroll
        for (int k = 0; k < 4; ++k) h[i][k] = xr[k * 64 + lane];
      }
      // 3) masks + update + square-accumulate (4 parallel fma chains)
      float acc[4];
#pragma unroll
      for (int k = 0; k < 4; ++k) {
        float a = 0.0f;
#pragma unroll
        for (int j = 0; j < 4; ++j) {
          float c  = cc[k][j];
          float cm = (fabsf(c) > thr) ? c : 0.0f;          // c * [|c|>eps*n]
          float bb = (c < -thr) ? etb[k][j] : 0.0f;        // eta*tb * [c<-eps*n]
          float w  = fmaf(eta_abs, cm, v[k][j]);           // v + eta*cc*m
          float xn = fmaf(inv, w, bb);                     // s + update (pre-renorm)
          v[k][j]  = xn;
          a = fmaf(xn, xn, a);
        }
        acc[k] = a;
      }
      // 4) wave-wide ||v||^2, n, thr, inv (div overlaps next iter's cmp/sel)
      float S = wave_sum_bcast((acc[0] + acc[1]) + (acc[2] + acc[3]));
      float n = fmaxf(sqrtf(S), EPS_NORM_F);
      float r = 1.0f / n;            // precise IEEE div
      thr = EPS_SIGN_F * n;
      // 5) out[t] = v * r  (off the recurrence critical path)
      {
        F4* orow = (F4*)(ob + (size_t)t * D);
#pragma unroll
        for (int k = 0; k < 4; ++k) {
          F4 o;
          o.v0 = v[k][0] * r; o.v1 = v[k][1] * r;
          o.v2 = v[k][2] * r; o.v3 = v[k][3] * r;
          orow[k * 64 + lane] = o;
        }
      }
      inv = r;
    }
  }
}

extern "C" void kernel_launch(void* const* d_in, const int* in_sizes, int n_in,
                              void* d_out, int out_size, void* d_ws, size_t ws_size,
                              hipStream_t stream) {
  const float* x         = (const float*)d_in[0];
  const float* tape_init = (const float*)d_in[1];
  const float* eta       = (const float*)d_in[2];
  const float* tbias     = (const float*)d_in[3];
  float* out = (float*)d_out;

  const int D = 1024;
  const int B = 8;
  const int T = in_sizes[0] / (B * D);   // 4096

  dim3 grid(B), block(64);               // one wave per chain
  hipLaunchKernelGGL(me_scan, grid, block, 0, stream,
                     x, tape_init, eta, tbias, out, T);
}